// Round 1
// baseline (2870.264 us; speedup 1.0000x reference)
//
#include <hip/hip_runtime.h>
#include <math.h>

#define HIDDEN 768
#define HEADS 12
#define HD 64
#define SEQ 2048
#define BATCH 2
#define KK 204
#define QB 16
#define NTH 512

// monotonic float->uint key (larger float => larger key)
__device__ __forceinline__ unsigned fkey(float f) {
    unsigned u = __float_as_uint(f);
    return u ^ ((unsigned)((int)u >> 31) | 0x80000000u);
}
__device__ __forceinline__ float fival(unsigned k) {
    unsigned u = k ^ ((k & 0x80000000u) ? 0x80000000u : 0xFFFFFFFFu);
    return __uint_as_float(u);
}

// ---------------------------------------------------------------------------
// y = A @ W^T + bias.  A:[M,K] row-major, W:[N,K] row-major.  M=4096,N=K=768.
// MODE 0: out[((b*HEADS+h)*SEQ+s)*HD+dh]   (Q,V layout)
// MODE 1: out[((b*HEADS+h)*HD+dh)*SEQ+s]   (K transposed layout)
// MODE 2: out[m*HIDDEN+n]                  (plain row-major)
// ---------------------------------------------------------------------------
template<int MODE>
__global__ __launch_bounds__(256)
void gemm_proj(const float* __restrict__ A, const float* __restrict__ W,
               const float* __restrict__ bias, float* __restrict__ out)
{
    const int K = HIDDEN;
    __shared__ float As[16][68];   // [k][m], stride 68 keeps 16B alignment
    __shared__ float Bs[16][68];   // [k][n]
    const int tid = threadIdx.x;
    const int n0 = blockIdx.x * 64;
    const int m0 = blockIdx.y * 64;
    const int lr = tid >> 2;          // 0..63
    const int lk = (tid & 3) << 2;    // 0,4,8,12
    const int ty = tid >> 4, tx = tid & 15;
    const int r0 = ty << 2, c0 = tx << 2;
    float acc[4][4] = {};
    for (int k0 = 0; k0 < K; k0 += 16) {
        const float4 av = *(const float4*)&A[(size_t)(m0 + lr) * K + k0 + lk];
        const float4 bv = *(const float4*)&W[(size_t)(n0 + lr) * K + k0 + lk];
        __syncthreads();
        As[lk+0][lr] = av.x; As[lk+1][lr] = av.y; As[lk+2][lr] = av.z; As[lk+3][lr] = av.w;
        Bs[lk+0][lr] = bv.x; Bs[lk+1][lr] = bv.y; Bs[lk+2][lr] = bv.z; Bs[lk+3][lr] = bv.w;
        __syncthreads();
        #pragma unroll
        for (int k = 0; k < 16; ++k) {
            const float4 a = *(const float4*)&As[k][r0];
            const float4 b = *(const float4*)&Bs[k][c0];
            const float aa[4] = {a.x, a.y, a.z, a.w};
            const float bb[4] = {b.x, b.y, b.z, b.w};
            #pragma unroll
            for (int i = 0; i < 4; ++i)
                #pragma unroll
                for (int j = 0; j < 4; ++j)
                    acc[i][j] += aa[i] * bb[j];
        }
    }

    if (MODE == 2) {
        #pragma unroll
        for (int i = 0; i < 4; ++i) {
            float4 v;
            v.x = acc[i][0] + bias[n0+c0+0];
            v.y = acc[i][1] + bias[n0+c0+1];
            v.z = acc[i][2] + bias[n0+c0+2];
            v.w = acc[i][3] + bias[n0+c0+3];
            *(float4*)&out[(size_t)(m0+r0+i)*HIDDEN + n0 + c0] = v;
        }
    } else if (MODE == 0) {
        const int h = n0 >> 6;   // whole block is one head (n0 is 64-aligned)
        #pragma unroll
        for (int i = 0; i < 4; ++i) {
            const int m = m0 + r0 + i;
            const int b = m >> 11, s = m & (SEQ-1);
            float4 v;
            v.x = acc[i][0] + bias[n0+c0+0];
            v.y = acc[i][1] + bias[n0+c0+1];
            v.z = acc[i][2] + bias[n0+c0+2];
            v.w = acc[i][3] + bias[n0+c0+3];
            *(float4*)&out[(((size_t)(b*HEADS + h)*SEQ + s) << 6) + c0] = v;
        }
    } else { // MODE 1: K transposed
        const int h = n0 >> 6;
        const int m = m0 + r0;
        const int b = m >> 11, s0 = m & (SEQ-1);
        #pragma unroll
        for (int j = 0; j < 4; ++j) {
            const float bb2 = bias[n0 + c0 + j];
            float4 v;
            v.x = acc[0][j] + bb2;
            v.y = acc[1][j] + bb2;
            v.z = acc[2][j] + bb2;
            v.w = acc[3][j] + bb2;
            *(float4*)&out[((size_t)(b*HEADS + h)*HD + c0 + j)*SEQ + s0] = v;
        }
    }
}

// ---------------------------------------------------------------------------
// Fused sparse attention: scores -> exact top-204 (radix select) -> softmax
// over survivors -> PV.  One 512-thread workgroup per (16 q-rows, h, b).
// ---------------------------------------------------------------------------
__global__ __launch_bounds__(NTH)
void sparse_attn(const float* __restrict__ Q, const float* __restrict__ Kt,
                 const float* __restrict__ V, float* __restrict__ AO)
{
    extern __shared__ float smem[];
    float*    scores   = smem;                                  // QB*SEQ
    float*    qlds     = smem + QB*SEQ;                         // HD*20 (transposed Q, padded)
    unsigned* hist     = (unsigned*)(qlds + HD*20);             // QB*256 (radix hist, reused as index list)
    float*    partials = (float*)(hist + QB*256);               // QB*32
    unsigned* cntarr   = (unsigned*)(partials + QB*32);         // QB*32
    unsigned* state    = cntarr + QB*32;                        // QB*8

    const int tid = threadIdx.x;
    const int q0 = blockIdx.x * QB;
    const int bh = blockIdx.z * HEADS + blockIdx.y;

    // ---- Q tile -> LDS (transposed [dh][q], row stride 20 floats)
    if (tid < 256) {
        const int r  = tid >> 4;
        const int c4 = (tid & 15) << 2;
        const float4 v = *(const float4*)&Q[(((size_t)bh*SEQ + q0 + r) << 6) + c4];
        qlds[(c4+0)*20 + r] = v.x;
        qlds[(c4+1)*20 + r] = v.y;
        qlds[(c4+2)*20 + r] = v.z;
        qlds[(c4+3)*20 + r] = v.w;
    }
    const int row = tid >> 5;     // 0..15: the q-row this thread helps select
    const int rt  = tid & 31;     // 0..31 within the row's 32-thread team
    if (rt == 0) {
        unsigned* st0 = state + row*8;
        st0[0] = 0;      // max key
        st0[1] = 0;      // radix prefix / final threshold key
        st0[2] = KK;     // remaining to take at/below current digit
        st0[3] = 0;      // count of elements equal to threshold
        st0[4] = SEQ;    // tie cut index (include equals with k <= icut)
        st0[6] = 0;      // total selected
    }
    __syncthreads();

    // ---- scores = Q K^T / 8 into LDS
    {
        const int tx = tid & 127, ty = tid >> 7;
        const int qq = ty << 2;                     // 4 q-rows per thread
        const float* kbase = Kt + (size_t)bh * HD * SEQ;
        for (int kc = 0; kc < SEQ; kc += 512) {
            const int kk0 = kc + (tx << 2);         // 4 k-cols per thread
            float acc[4][4] = {};
            const float* kp = kbase + kk0;
            #pragma unroll 8
            for (int dh = 0; dh < HD; ++dh) {
                const float4 kv = *(const float4*)(kp + (size_t)dh * SEQ);
                const float4 qv = *(const float4*)&qlds[dh*20 + qq];
                const float ka[4] = {kv.x, kv.y, kv.z, kv.w};
                const float qa[4] = {qv.x, qv.y, qv.z, qv.w};
                #pragma unroll
                for (int i = 0; i < 4; ++i)
                    #pragma unroll
                    for (int j = 0; j < 4; ++j)
                        acc[i][j] += qa[i] * ka[j];
            }
            #pragma unroll
            for (int i = 0; i < 4; ++i) {
                float4 sv;
                sv.x = acc[i][0]*0.125f; sv.y = acc[i][1]*0.125f;
                sv.z = acc[i][2]*0.125f; sv.w = acc[i][3]*0.125f;
                *(float4*)&scores[(qq+i)*SEQ + kk0] = sv;
            }
        }
    }
    __syncthreads();

    unsigned* st = state + row*8;
    const float* srow = scores + row*SEQ;
    const int base = rt << 6;     // contiguous 64-element chunk per thread

    // ---- row max (for softmax)
    {
        unsigned mk = 0;
        #pragma unroll 8
        for (int j = 0; j < 64; ++j) mk = max(mk, fkey(srow[base + j]));
        atomicMax(&st[0], mk);
    }

    // ---- exact top-KK threshold via 4-pass radix select on sortable keys
    unsigned prefix = 0;
    for (int p = 0; p < 4; ++p) {
        const int shift = 24 - (p << 3);
        const unsigned maskHi = (p == 0) ? 0u : (0xFFFFFFFFu << (shift + 8));
        for (int j2 = rt; j2 < 256; j2 += 32) hist[row*256 + j2] = 0;
        __syncthreads();
        prefix = st[1];
        for (int j = 0; j < 64; ++j) {
            const unsigned u = fkey(srow[base + j]);
            if ((u & maskHi) == prefix)
                atomicAdd(&hist[row*256 + ((u >> shift) & 255u)], 1u);
        }
        __syncthreads();
        if (rt == 0) {
            const unsigned rem = st[2];
            unsigned cum = 0;
            int bsel = 0;
            for (int bin = 255; bin >= 0; --bin) {
                const unsigned c = hist[row*256 + bin];
                if (cum + c >= rem) { bsel = bin; break; }
                cum += c;
            }
            st[2] = rem - cum;                       // still needed within bin
            st[1] = prefix | ((unsigned)bsel << shift);
        }
        __syncthreads();
    }
    const unsigned t = st[1];       // key of the KK-th largest
    const unsigned rem_eq = st[2];  // how many ==t to include

    // ---- tie handling (lowest-index-first like lax.top_k); almost never hit
    {
        unsigned cE = 0;
        for (int j = 0; j < 64; ++j) cE += (fkey(srow[base + j]) == t) ? 1u : 0u;
        if (cE) atomicAdd(&st[3], cE);
    }
    __syncthreads();
    if (rt == 0 && st[3] > rem_eq) {
        unsigned c = 0;
        for (int k = 0; k < SEQ; ++k)
            if (fkey(srow[k]) == t) { if (++c == rem_eq) { st[4] = (unsigned)k; break; } }
    }
    __syncthreads();
    const int icut = (int)st[4];
    const float mrow = fival(st[0]);

    // ---- ordered compaction of selected indices + deterministic exp-sum
    {
        int cnt = 0;
        #pragma unroll 4
        for (int j = 0; j < 64; ++j) {
            const unsigned u = fkey(srow[base + j]);
            if (u > t || (u == t && (base + j) <= icut)) ++cnt;
        }
        cntarr[row*32 + rt] = (unsigned)cnt;
    }
    __syncthreads();
    if (rt == 0) {                 // exclusive prefix over 32 chunk counts
        unsigned s = 0;
        for (int i2 = 0; i2 < 32; ++i2) {
            const unsigned c = cntarr[row*32 + i2];
            cntarr[row*32 + i2] = s;
            s += c;
        }
    }
    __syncthreads();
    {
        int pos = (int)cntarr[row*32 + rt];
        float psum = 0.f;
        for (int j = 0; j < 64; ++j) {
            const int k = base + j;
            const float sv = srow[k];
            const unsigned u = fkey(sv);
            if (u > t || (u == t && k <= icut)) {
                if (pos < 256) hist[row*256 + pos] = (unsigned)k;  // index list
                ++pos;
                psum += __expf(sv - mrow);
            }
        }
        partials[row*32 + rt] = psum;
        if (rt == 31) st[6] = (unsigned)pos;   // total selected (== KK)
    }
    __syncthreads();
    for (int s2 = 16; s2 >= 1; s2 >>= 1) {     // deterministic tree reduction
        if (rt < s2) partials[row*32 + rt] += partials[row*32 + rt + s2];
        __syncthreads();
    }
    if (rt == 0) st[5] = __float_as_uint(1.0f / partials[row*32]);
    __syncthreads();

    // ---- PV: one wave per row (lane = dh), only the selected ~204 V rows
    {
        const int w = tid >> 6, d = tid & 63;
        const float* vbase = V + ((size_t)bh * SEQ << 6);
        for (int rr = w; rr < QB; rr += 8) {
            const unsigned* stt = state + rr*8;
            const float mr  = fival(stt[0]);
            const float inv = __uint_as_float(stt[5]);
            const int   nk  = (int)stt[6];
            const float* sr = scores + rr*SEQ;
            const unsigned* il = hist + rr*256;
            float acc = 0.f;
            for (int j = 0; j < nk && j < 256; ++j) {
                const int k = (int)il[j];
                const float wgt = __expf(sr[k] - mr);
                acc += wgt * vbase[((size_t)k << 6) + d];
            }
            acc *= inv;
            AO[((size_t)blockIdx.z*SEQ + q0 + rr)*HIDDEN + blockIdx.y*HD + d] = acc;
        }
    }
}

// ---------------------------------------------------------------------------
extern "C" void kernel_launch(void* const* d_in, const int* in_sizes, int n_in,
                              void* d_out, int out_size, void* d_ws, size_t ws_size,
                              hipStream_t stream)
{
    const float* x  = (const float*)d_in[0];
    const float* Wq = (const float*)d_in[1];
    const float* bq = (const float*)d_in[2];
    const float* Wk = (const float*)d_in[3];
    const float* bk = (const float*)d_in[4];
    const float* Wv = (const float*)d_in[5];
    const float* bv = (const float*)d_in[6];
    const float* Wo = (const float*)d_in[7];
    const float* bo = (const float*)d_in[8];

    float* ws = (float*)d_ws;
    const size_t SZ = (size_t)BATCH * HEADS * SEQ * HD;   // 3.1M floats each
    float* Qb  = ws;
    float* Ktb = ws + SZ;
    float* Vb  = ws + 2*SZ;
    float* AOb = ws + 3*SZ;

    dim3 gg(HIDDEN/64, (BATCH*SEQ)/64, 1);
    gemm_proj<0><<<gg, 256, 0, stream>>>(x, Wq, bq, Qb);   // Q  [bh][s][dh]
    gemm_proj<1><<<gg, 256, 0, stream>>>(x, Wk, bk, Ktb);  // Kt [bh][dh][s]
    gemm_proj<0><<<gg, 256, 0, stream>>>(x, Wv, bv, Vb);   // V  [bh][s][dh]

    const size_t shbytes = (size_t)(QB*SEQ + HD*20 + QB*256 + QB*32 + QB*32 + QB*8) * 4;
    hipFuncSetAttribute((const void*)sparse_attn,
                        hipFuncAttributeMaxDynamicSharedMemorySize, (int)shbytes);
    sparse_attn<<<dim3(SEQ/QB, HEADS, BATCH), NTH, shbytes, stream>>>(Qb, Ktb, Vb, AOb);

    gemm_proj<2><<<gg, 256, 0, stream>>>(AOb, Wo, bo, (float*)d_out);
}

// Round 3
// 1139.076 us; speedup vs baseline: 2.5198x; 2.5198x over previous
//
#include <hip/hip_runtime.h>
#include <math.h>

#define HIDDEN 768
#define HEADS 12
#define HD 64
#define SEQ 2048
#define BATCH 2
#define KK 204
#define QB 16
#define NTH 512

// monotonic float->uint key (larger float => larger key)
__device__ __forceinline__ unsigned fkey(float f) {
    unsigned u = __float_as_uint(f);
    return u ^ ((unsigned)((int)u >> 31) | 0x80000000u);
}
__device__ __forceinline__ float fival(unsigned k) {
    unsigned u = k ^ ((k & 0x80000000u) ? 0x80000000u : 0xFFFFFFFFu);
    return __uint_as_float(u);
}

// ---------------------------------------------------------------------------
// y = A @ W^T + bias.  A:[M,K] row-major, W:[N,K] row-major.  M=4096,N=K=768.
// MODE 0: out[((b*HEADS+h)*SEQ+s)*HD+dh]   (Q,V layout)
// MODE 1: out[((b*HEADS+h)*HD+dh)*SEQ+s]   (K transposed layout)
// MODE 2: out[m*HIDDEN+n]                  (plain row-major)
// ---------------------------------------------------------------------------
template<int MODE>
__global__ __launch_bounds__(256)
void gemm_proj(const float* __restrict__ A, const float* __restrict__ W,
               const float* __restrict__ bias, float* __restrict__ out)
{
    const int K = HIDDEN;
    __shared__ float As[16][68];
    __shared__ float Bs[16][68];
    const int tid = threadIdx.x;
    const int n0 = blockIdx.x * 64;
    const int m0 = blockIdx.y * 64;
    const int lr = tid >> 2;
    const int lk = (tid & 3) << 2;
    const int ty = tid >> 4, tx = tid & 15;
    const int r0 = ty << 2, c0 = tx << 2;
    float acc[4][4] = {};
    for (int k0 = 0; k0 < K; k0 += 16) {
        const float4 av = *(const float4*)&A[(size_t)(m0 + lr) * K + k0 + lk];
        const float4 bv = *(const float4*)&W[(size_t)(n0 + lr) * K + k0 + lk];
        __syncthreads();
        As[lk+0][lr] = av.x; As[lk+1][lr] = av.y; As[lk+2][lr] = av.z; As[lk+3][lr] = av.w;
        Bs[lk+0][lr] = bv.x; Bs[lk+1][lr] = bv.y; Bs[lk+2][lr] = bv.z; Bs[lk+3][lr] = bv.w;
        __syncthreads();
        #pragma unroll
        for (int k = 0; k < 16; ++k) {
            const float4 a = *(const float4*)&As[k][r0];
            const float4 b = *(const float4*)&Bs[k][c0];
            const float aa[4] = {a.x, a.y, a.z, a.w};
            const float bb[4] = {b.x, b.y, b.z, b.w};
            #pragma unroll
            for (int i = 0; i < 4; ++i)
                #pragma unroll
                for (int j = 0; j < 4; ++j)
                    acc[i][j] += aa[i] * bb[j];
        }
    }

    if (MODE == 2) {
        #pragma unroll
        for (int i = 0; i < 4; ++i) {
            float4 v;
            v.x = acc[i][0] + bias[n0+c0+0];
            v.y = acc[i][1] + bias[n0+c0+1];
            v.z = acc[i][2] + bias[n0+c0+2];
            v.w = acc[i][3] + bias[n0+c0+3];
            *(float4*)&out[(size_t)(m0+r0+i)*HIDDEN + n0 + c0] = v;
        }
    } else if (MODE == 0) {
        const int h = n0 >> 6;
        #pragma unroll
        for (int i = 0; i < 4; ++i) {
            const int m = m0 + r0 + i;
            const int b = m >> 11, s = m & (SEQ-1);
            float4 v;
            v.x = acc[i][0] + bias[n0+c0+0];
            v.y = acc[i][1] + bias[n0+c0+1];
            v.z = acc[i][2] + bias[n0+c0+2];
            v.w = acc[i][3] + bias[n0+c0+3];
            *(float4*)&out[(((size_t)(b*HEADS + h)*SEQ + s) << 6) + c0] = v;
        }
    } else { // MODE 1: K transposed
        const int h = n0 >> 6;
        const int m = m0 + r0;
        const int b = m >> 11, s0 = m & (SEQ-1);
        #pragma unroll
        for (int j = 0; j < 4; ++j) {
            const float bb2 = bias[n0 + c0 + j];
            float4 v;
            v.x = acc[0][j] + bb2;
            v.y = acc[1][j] + bb2;
            v.z = acc[2][j] + bb2;
            v.w = acc[3][j] + bb2;
            *(float4*)&out[((size_t)(b*HEADS + h)*HD + c0 + j)*SEQ + s0] = v;
        }
    }
}

// ---------------------------------------------------------------------------
// Fused sparse attention. One 512-thread workgroup per (16 q-rows, h, b).
// Select phase: scores -> 64 keys/thread in VGPRs (conflict-free b128 reads)
// -> 4-pass radix select (shfl-parallel bin scan) -> compaction -> PV.
// ---------------------------------------------------------------------------
__global__ __launch_bounds__(NTH)
void sparse_attn(const float* __restrict__ Q, const float* __restrict__ Kt,
                 const float* __restrict__ V, float* __restrict__ AO)
{
    extern __shared__ float smem[];
    float*    scores = smem;                          // QB*SEQ
    float*    qlds   = smem + QB*SEQ;                 // HD*20
    unsigned* hist   = (unsigned*)(qlds + HD*20);     // QB*256 (radix hist / index list)
    unsigned* state  = hist + QB*256;                 // QB*8

    const int tid = threadIdx.x;
    const int q0 = blockIdx.x * QB;
    const int bh = blockIdx.z * HEADS + blockIdx.y;

    // ---- Q tile -> LDS (transposed [dh][q], row stride 20 floats)
    if (tid < 256) {
        const int r  = tid >> 4;
        const int c4 = (tid & 15) << 2;
        const float4 v = *(const float4*)&Q[(((size_t)bh*SEQ + q0 + r) << 6) + c4];
        qlds[(c4+0)*20 + r] = v.x;
        qlds[(c4+1)*20 + r] = v.y;
        qlds[(c4+2)*20 + r] = v.z;
        qlds[(c4+3)*20 + r] = v.w;
    }
    const int row = tid >> 5;     // 0..15
    const int rt  = tid & 31;     // 0..31 team lane
    if (rt == 0) {
        unsigned* st0 = state + row*8;
        st0[1] = 0;      // radix prefix / final threshold key
        st0[2] = KK;     // remaining to take
        st0[4] = SEQ;    // tie cut index
    }
    __syncthreads();

    // ---- scores = Q K^T / 8 into LDS
    {
        const int tx = tid & 127, ty = tid >> 7;
        const int qq = ty << 2;
        const float* kbase = Kt + (size_t)bh * HD * SEQ;
        for (int kc = 0; kc < SEQ; kc += 512) {
            const int kk0 = kc + (tx << 2);
            float acc[4][4] = {};
            const float* kp = kbase + kk0;
            #pragma unroll 8
            for (int dh = 0; dh < HD; ++dh) {
                const float4 kv = *(const float4*)(kp + (size_t)dh * SEQ);
                const float4 qv = *(const float4*)&qlds[dh*20 + qq];
                const float ka[4] = {kv.x, kv.y, kv.z, kv.w};
                const float qa[4] = {qv.x, qv.y, qv.z, qv.w};
                #pragma unroll
                for (int i = 0; i < 4; ++i)
                    #pragma unroll
                    for (int j = 0; j < 4; ++j)
                        acc[i][j] += qa[i] * ka[j];
            }
            #pragma unroll
            for (int i = 0; i < 4; ++i) {
                float4 sv;
                sv.x = acc[i][0]*0.125f; sv.y = acc[i][1]*0.125f;
                sv.z = acc[i][2]*0.125f; sv.w = acc[i][3]*0.125f;
                *(float4*)&scores[(qq+i)*SEQ + kk0] = sv;
            }
        }
    }
    __syncthreads();

    unsigned* st = state + row*8;
    const float4* srow4 = (const float4*)(scores + row*SEQ);

    // ---- load this thread's 64 elements ONCE as sortable keys (registers).
    // float4 index rt+32j: 8-lane quads read contiguous 128B -> conflict-free.
    // element k = 4*rt + 128*j + e
    unsigned key[64];
    #pragma unroll
    for (int j = 0; j < 16; ++j) {
        const float4 v = srow4[rt + 32*j];
        key[4*j+0] = fkey(v.x); key[4*j+1] = fkey(v.y);
        key[4*j+2] = fkey(v.z); key[4*j+3] = fkey(v.w);
    }

    // ---- row max via shfl reduce
    unsigned mk = 0;
    #pragma unroll
    for (int e = 0; e < 64; ++e) mk = max(mk, key[e]);
    #pragma unroll
    for (int d = 16; d >= 1; d >>= 1)
        mk = max(mk, (unsigned)__shfl_xor((int)mk, d, 32));
    const float mrow = fival(mk);
    if (rt == 0) st[0] = mk;           // for PV phase (cross-team)

    // ---- exact top-KK threshold: 4-pass radix select on 8-bit digits
    for (int p = 0; p < 4; ++p) {
        const int shift = 24 - (p << 3);
        const unsigned maskHi = (p == 0) ? 0u : (0xFFFFFFFFu << (shift + 8));
        const unsigned prefix = st[1];
        const unsigned rem    = st[2];
        // zero hist
        #pragma unroll
        for (int j2 = 0; j2 < 8; ++j2) hist[row*256 + rt + 32*j2] = 0;
        __syncthreads();
        #pragma unroll
        for (int e = 0; e < 64; ++e) {
            const unsigned u = key[e];
            if ((u & maskHi) == prefix)
                atomicAdd(&hist[row*256 + ((u >> shift) & 255u)], 1u);
        }
        __syncthreads();
        // parallel descending scan: thread rt owns bins [255-8rt .. 248-8rt]
        unsigned hloc[8]; unsigned s_local = 0;
        #pragma unroll
        for (int e = 0; e < 8; ++e) {
            hloc[e] = hist[row*256 + 255 - 8*rt - e];
            s_local += hloc[e];
        }
        unsigned inc = s_local;
        #pragma unroll
        for (int d = 1; d < 32; d <<= 1) {
            const unsigned o = (unsigned)__shfl_up((int)inc, (unsigned)d, 32);
            if (rt >= d) inc += o;
        }
        const unsigned s_above = inc - s_local;   // count in bins above my chunk
        if (s_above < rem && s_above + s_local >= rem) {
            unsigned cum = s_above;
            #pragma unroll
            for (int e = 0; e < 8; ++e) {
                const unsigned c = hloc[e];
                if (cum + c >= rem) {
                    st[1] = prefix | ((unsigned)(255 - 8*rt - e) << shift);
                    st[2] = rem - cum;
                    break;
                }
                cum += c;
            }
        }
        __syncthreads();
    }
    const unsigned t      = st[1];   // key of the KK-th largest
    const unsigned rem_eq = st[2];   // how many ==t to include

    // ---- tie handling (lowest-index-first, like lax.top_k); rare path
    {
        unsigned cE = 0;
        #pragma unroll
        for (int e = 0; e < 64; ++e) cE += (key[e] == t) ? 1u : 0u;
        #pragma unroll
        for (int d = 16; d >= 1; d >>= 1)
            cE += (unsigned)__shfl_xor((int)cE, d, 32);
        if (rt == 0 && cE > rem_eq) {
            const float* srow = scores + row*SEQ;
            unsigned c = 0;
            for (int k = 0; k < SEQ; ++k)
                if (fkey(srow[k]) == t) { if (++c == rem_eq) { st[4] = (unsigned)k; break; } }
        }
    }
    __syncthreads();
    const int icut = (int)st[4];

    // ---- compaction of selected indices + deterministic exp-sum (all in regs)
    {
        int cnt = 0;
        #pragma unroll
        for (int jj = 0; jj < 64; ++jj) {
            const int k = 4*rt + 128*(jj >> 2) + (jj & 3);
            const unsigned u = key[jj];
            if (u > t || (u == t && k <= icut)) ++cnt;
        }
        int pos = cnt;
        #pragma unroll
        for (int d = 1; d < 32; d <<= 1) {
            const int o = __shfl_up(pos, (unsigned)d, 32);
            if (rt >= d) pos += o;
        }
        pos -= cnt;    // exclusive prefix
        float psum = 0.f;
        #pragma unroll
        for (int jj = 0; jj < 64; ++jj) {
            const int k = 4*rt + 128*(jj >> 2) + (jj & 3);
            const unsigned u = key[jj];
            if (u > t || (u == t && k <= icut)) {
                hist[row*256 + pos] = (unsigned)k;
                ++pos;
                psum += __expf(fival(u) - mrow);
            }
        }
        if (rt == 31) st[6] = (unsigned)pos;   // total selected (== KK)
        #pragma unroll
        for (int d = 16; d >= 1; d >>= 1)
            psum += __shfl_xor(psum, d, 32);
        if (rt == 0) st[5] = __float_as_uint(1.0f / psum);
    }
    __syncthreads();

    // ---- PV: one wave per row (lane = dh), only the selected ~204 V rows
    {
        const int w = tid >> 6, d = tid & 63;
        const float* vbase = V + ((size_t)bh * SEQ << 6);
        for (int rr = w; rr < QB; rr += 8) {
            const unsigned* stt = state + rr*8;
            const float mr  = fival(stt[0]);
            const float inv = __uint_as_float(stt[5]);
            const int   nk  = (int)stt[6];
            const float* sr = scores + rr*SEQ;
            const unsigned* il = hist + rr*256;
            float acc = 0.f;
            for (int j = 0; j < nk && j < 256; ++j) {
                const int k = (int)il[j];
                const float wgt = __expf(sr[k] - mr);
                acc += wgt * vbase[((size_t)k << 6) + d];
            }
            acc *= inv;
            AO[((size_t)blockIdx.z*SEQ + q0 + rr)*HIDDEN + blockIdx.y*HD + d] = acc;
        }
    }
}

// ---------------------------------------------------------------------------
extern "C" void kernel_launch(void* const* d_in, const int* in_sizes, int n_in,
                              void* d_out, int out_size, void* d_ws, size_t ws_size,
                              hipStream_t stream)
{
    const float* x  = (const float*)d_in[0];
    const float* Wq = (const float*)d_in[1];
    const float* bq = (const float*)d_in[2];
    const float* Wk = (const float*)d_in[3];
    const float* bk = (const float*)d_in[4];
    const float* Wv = (const float*)d_in[5];
    const float* bv = (const float*)d_in[6];
    const float* Wo = (const float*)d_in[7];
    const float* bo = (const float*)d_in[8];

    float* ws = (float*)d_ws;
    const size_t SZ = (size_t)BATCH * HEADS * SEQ * HD;
    float* Qb  = ws;
    float* Ktb = ws + SZ;
    float* Vb  = ws + 2*SZ;
    float* AOb = ws + 3*SZ;

    dim3 gg(HIDDEN/64, (BATCH*SEQ)/64, 1);
    gemm_proj<0><<<gg, 256, 0, stream>>>(x, Wq, bq, Qb);   // Q  [bh][s][dh]
    gemm_proj<1><<<gg, 256, 0, stream>>>(x, Wk, bk, Ktb);  // Kt [bh][dh][s]
    gemm_proj<0><<<gg, 256, 0, stream>>>(x, Wv, bv, Vb);   // V  [bh][s][dh]

    const size_t shbytes = (size_t)(QB*SEQ + HD*20) * 4 + (size_t)(QB*256 + QB*8) * 4;
    hipFuncSetAttribute((const void*)sparse_attn,
                        hipFuncAttributeMaxDynamicSharedMemorySize, (int)shbytes);
    sparse_attn<<<dim3(SEQ/QB, HEADS, BATCH), NTH, shbytes, stream>>>(Qb, Ktb, Vb, AOb);

    gemm_proj<2><<<gg, 256, 0, stream>>>(AOb, Wo, bo, (float*)d_out);
}

// Round 4
// 625.192 us; speedup vs baseline: 4.5910x; 1.8220x over previous
//
#include <hip/hip_runtime.h>
#include <math.h>

#define HIDDEN 768
#define HEADS 12
#define HD 64
#define SEQ 2048
#define BATCH 2
#define KK 204
#define QB 16
#define NTH 512

typedef __attribute__((ext_vector_type(8))) short short8;
typedef __attribute__((ext_vector_type(4))) float f32x4;

// monotonic float->uint key (larger float => larger key)
__device__ __forceinline__ unsigned fkey(float f) {
    unsigned u = __float_as_uint(f);
    return u ^ ((unsigned)((int)u >> 31) | 0x80000000u);
}
__device__ __forceinline__ float fival(unsigned k) {
    unsigned u = k ^ ((k & 0x80000000u) ? 0x80000000u : 0xFFFFFFFFu);
    return __uint_as_float(u);
}
__device__ __forceinline__ unsigned short bf16h(float f) {
    unsigned u = __float_as_uint(f);
    return (unsigned short)((u + 0x7FFFu + ((u >> 16) & 1u)) >> 16);
}
__device__ __forceinline__ float bf16f(unsigned short h) {
    return __uint_as_float(((unsigned)h) << 16);
}

// swizzled fp32 score LDS index (float4-group XOR row&7) — row stride 2048
#define SIDX(r,k) (((r)<<11) + (((((k)>>2) ^ ((r)&7))) << 2) + ((k)&3))

// ---------------------------------------------------------------------------
// Convert fp32 row-major [rows x 768] into MFMA fragment layout bf16 hi/lo:
// out[(rblk*24 + kc)*64 + lane][j] with lane = kg*16 + (r&15), j = k&7.
// Used for A-operands (x) and B-operands (W, since both index (row, k)).
// ---------------------------------------------------------------------------
__global__ __launch_bounds__(256)
void cvt_frag(const float* __restrict__ in, unsigned short* __restrict__ oh,
              unsigned short* __restrict__ ol, int rows)
{
    const int t = blockIdx.x * 256 + threadIdx.x;
    if (t >= rows * 96) return;
    const int lane = t & 63;
    const int kc   = (t >> 6) % 24;
    const int rblk = t / (24 * 64);
    const int r = rblk * 16 + (lane & 15);
    const int k = kc * 32 + (lane >> 4) * 8;
    const float4 a = *(const float4*)&in[(size_t)r * 768 + k];
    const float4 b = *(const float4*)&in[(size_t)r * 768 + k + 4];
    const float v[8] = {a.x, a.y, a.z, a.w, b.x, b.y, b.z, b.w};
    short8 sh, sl;
    #pragma unroll
    for (int j = 0; j < 8; ++j) {
        const unsigned short hh = bf16h(v[j]);
        sh[j] = (short)hh;
        sl[j] = (short)bf16h(v[j] - bf16f(hh));
    }
    *(short8*)&oh[(size_t)t * 8] = sh;
    *(short8*)&ol[(size_t)t * 8] = sl;
}

// ---------------------------------------------------------------------------
// Projection GEMM via split-bf16 MFMA: y = x @ W^T + b, M=4096, N=K=768.
// MODE 0: output bf16 hi/lo in attn Q/K fragment layout [bh][t][ks][lane][8]
// MODE 1: output bf16 hi in attn V  fragment layout [bh][dt][kc2][lane][8]
// ---------------------------------------------------------------------------
template<int MODE>
__global__ __launch_bounds__(256)
void proj_mfma(const unsigned short* __restrict__ Ah, const unsigned short* __restrict__ Al,
               const unsigned short* __restrict__ Bh, const unsigned short* __restrict__ Bl,
               const float* __restrict__ bias,
               unsigned short* __restrict__ Oh, unsigned short* __restrict__ Ol)
{
    const int w = threadIdx.x >> 6, lane = threadIdx.x & 63;
    const int n0 = blockIdx.x * 64;
    const int m0 = blockIdx.y * 64 + w * 16;
    const int mblk = m0 >> 4;
    f32x4 acc[4] = {};
    for (int kc = 0; kc < 24; ++kc) {
        const short8 ah = *(const short8*)&Ah[((size_t)(mblk * 24 + kc) * 64 + lane) * 8];
        const short8 al = *(const short8*)&Al[((size_t)(mblk * 24 + kc) * 64 + lane) * 8];
        #pragma unroll
        for (int nt = 0; nt < 4; ++nt) {
            const int nblk = (n0 >> 4) + nt;
            const short8 bh8 = *(const short8*)&Bh[((size_t)(nblk * 24 + kc) * 64 + lane) * 8];
            const short8 bl8 = *(const short8*)&Bl[((size_t)(nblk * 24 + kc) * 64 + lane) * 8];
            acc[nt] = __builtin_amdgcn_mfma_f32_16x16x32_bf16(ah, bh8, acc[nt], 0, 0, 0);
            acc[nt] = __builtin_amdgcn_mfma_f32_16x16x32_bf16(ah, bl8, acc[nt], 0, 0, 0);
            acc[nt] = __builtin_amdgcn_mfma_f32_16x16x32_bf16(al, bh8, acc[nt], 0, 0, 0);
        }
    }
    const int col = lane & 15, rg = lane >> 4;
    #pragma unroll
    for (int nt = 0; nt < 4; ++nt) {
        const int n = n0 + nt * 16 + col;
        const int h = n >> 6, dh = n & 63;
        const float bb = bias[n];
        #pragma unroll
        for (int r = 0; r < 4; ++r) {
            const int m = m0 + rg * 4 + r;
            const int b = m >> 11, s = m & (SEQ - 1);
            const float v = acc[nt][r] + bb;
            const unsigned short vh = bf16h(v);
            if (MODE == 0) {
                const int t = s >> 4, colq = s & 15;
                const int ks = dh >> 5, kg = (dh >> 3) & 3, j = dh & 7;
                const size_t addr = ((((size_t)(b * HEADS + h) * 128 + t) * 2 + ks) * 64 + kg * 16 + colq) * 8 + j;
                Oh[addr] = vh;
                Ol[addr] = bf16h(v - bf16f(vh));
            } else {
                const int dt = dh >> 4, colv = dh & 15;
                const int kc2 = s >> 5, kg = (s >> 3) & 3, j = s & 7;
                const size_t addr = ((((size_t)(b * HEADS + h) * 4 + dt) * 64 + kc2) * 64 + kg * 16 + colv) * 8 + j;
                Oh[addr] = vh;
            }
        }
    }
}

// ---------------------------------------------------------------------------
// Output GEMM: out = AO @ Wo^T + bo (fp32 out), AO/Wo in fragment layout.
// ---------------------------------------------------------------------------
__global__ __launch_bounds__(256)
void gemm_out(const unsigned short* __restrict__ Ah, const unsigned short* __restrict__ Al,
              const unsigned short* __restrict__ Bh, const unsigned short* __restrict__ Bl,
              const float* __restrict__ bias, float* __restrict__ out)
{
    const int w = threadIdx.x >> 6, lane = threadIdx.x & 63;
    const int n0 = blockIdx.x * 64;
    const int m0 = blockIdx.y * 64 + w * 16;
    const int mblk = m0 >> 4;
    f32x4 acc[4] = {};
    for (int kc = 0; kc < 24; ++kc) {
        const short8 ah = *(const short8*)&Ah[((size_t)(mblk * 24 + kc) * 64 + lane) * 8];
        const short8 al = *(const short8*)&Al[((size_t)(mblk * 24 + kc) * 64 + lane) * 8];
        #pragma unroll
        for (int nt = 0; nt < 4; ++nt) {
            const int nblk = (n0 >> 4) + nt;
            const short8 bh8 = *(const short8*)&Bh[((size_t)(nblk * 24 + kc) * 64 + lane) * 8];
            const short8 bl8 = *(const short8*)&Bl[((size_t)(nblk * 24 + kc) * 64 + lane) * 8];
            acc[nt] = __builtin_amdgcn_mfma_f32_16x16x32_bf16(ah, bh8, acc[nt], 0, 0, 0);
            acc[nt] = __builtin_amdgcn_mfma_f32_16x16x32_bf16(ah, bl8, acc[nt], 0, 0, 0);
            acc[nt] = __builtin_amdgcn_mfma_f32_16x16x32_bf16(al, bh8, acc[nt], 0, 0, 0);
        }
    }
    const int col = lane & 15, rg = lane >> 4;
    #pragma unroll
    for (int nt = 0; nt < 4; ++nt) {
        const int n = n0 + nt * 16 + col;
        const float bb = bias[n];
        #pragma unroll
        for (int r = 0; r < 4; ++r) {
            const int m = m0 + rg * 4 + r;
            out[(size_t)m * HIDDEN + n] = acc[nt][r] + bb;
        }
    }
}

// ---------------------------------------------------------------------------
// Fused sparse attention, MFMA edition. 512 thr / (16 q-rows, h, b).
// A: scores via split-bf16 MFMA -> swizzled LDS. B: exact top-204 radix
// select (keys in VGPRs). C: dense P (bf16 hi/lo, overlaying scores) ->
// PV via MFMA -> normalized AO in fragment layout (bf16 hi/lo).
// ---------------------------------------------------------------------------
__global__ __launch_bounds__(NTH)
void sparse_attn(const unsigned short* __restrict__ Qfh, const unsigned short* __restrict__ Qfl,
                 const unsigned short* __restrict__ Kfh, const unsigned short* __restrict__ Kfl,
                 const unsigned short* __restrict__ Vf,
                 unsigned short* __restrict__ AOh, unsigned short* __restrict__ AOl)
{
    extern __shared__ float smem[];
    float*    scores = smem;                           // 16*2048 f32 swizzled; later Ph/Pl overlay
    unsigned* hist   = (unsigned*)(smem + QB * SEQ);   // 16*256 (radix) / PV partial-C (4KB)
    unsigned* state  = hist + QB * 256;                // 16*8

    const int tid = threadIdx.x;
    const int wv = tid >> 6, lane = tid & 63;
    const int qb = blockIdx.x;
    const int q0 = qb * QB;
    const int h = blockIdx.y, b = blockIdx.z;
    const int bh = b * HEADS + h;

    if (tid < QB) {
        unsigned* s0 = state + tid * 8;
        s0[1] = 0; s0[2] = KK; s0[4] = SEQ;
    }

    // ---- Phase A: scores = Q K^T / 8 (6 MFMA per 16x16 tile: hh,hl,lh over 2 ksteps)
    {
        const size_t qbase = ((size_t)bh * 128 + qb) * 1024;
        const short8 qh0 = *(const short8*)&Qfh[qbase + lane * 8];
        const short8 qh1 = *(const short8*)&Qfh[qbase + 512 + lane * 8];
        const short8 ql0 = *(const short8*)&Qfl[qbase + lane * 8];
        const short8 ql1 = *(const short8*)&Qfl[qbase + 512 + lane * 8];
        const int col = lane & 15, rg = lane >> 4;
        for (int i = 0; i < 16; ++i) {
            const int t = wv * 16 + i;
            const size_t kb = ((size_t)bh * 128 + t) * 1024 + lane * 8;
            const short8 kh0 = *(const short8*)&Kfh[kb];
            const short8 kh1 = *(const short8*)&Kfh[kb + 512];
            const short8 kl0 = *(const short8*)&Kfl[kb];
            const short8 kl1 = *(const short8*)&Kfl[kb + 512];
            f32x4 c = {};
            c = __builtin_amdgcn_mfma_f32_16x16x32_bf16(qh0, kh0, c, 0, 0, 0);
            c = __builtin_amdgcn_mfma_f32_16x16x32_bf16(qh1, kh1, c, 0, 0, 0);
            c = __builtin_amdgcn_mfma_f32_16x16x32_bf16(qh0, kl0, c, 0, 0, 0);
            c = __builtin_amdgcn_mfma_f32_16x16x32_bf16(qh1, kl1, c, 0, 0, 0);
            c = __builtin_amdgcn_mfma_f32_16x16x32_bf16(ql0, kh0, c, 0, 0, 0);
            c = __builtin_amdgcn_mfma_f32_16x16x32_bf16(ql1, kh1, c, 0, 0, 0);
            const int k = t * 16 + col;
            #pragma unroll
            for (int r = 0; r < 4; ++r) {
                const int row = rg * 4 + r;
                scores[SIDX(row, k)] = c[r] * 0.125f;
            }
        }
    }
    __syncthreads();

    // ---- Phase B: exact top-KK per row (radix select on keys in VGPRs)
    const int row = tid >> 5, rt = tid & 31;
    unsigned* st = state + row * 8;
    const int cx = row & 7;
    unsigned key[64];
    {
        const float4* srow4 = (const float4*)(scores + (row << 11));
        #pragma unroll
        for (int j = 0; j < 16; ++j) {
            const float4 v = srow4[rt + 32 * j];
            key[4*j+0] = fkey(v.x); key[4*j+1] = fkey(v.y);
            key[4*j+2] = fkey(v.z); key[4*j+3] = fkey(v.w);
        }
    }
    unsigned mk = 0;
    #pragma unroll
    for (int e = 0; e < 64; ++e) mk = max(mk, key[e]);
    #pragma unroll
    for (int d = 16; d >= 1; d >>= 1)
        mk = max(mk, (unsigned)__shfl_xor((int)mk, d, 32));
    const float mrow = fival(mk);

    for (int p = 0; p < 4; ++p) {
        const int shift = 24 - (p << 3);
        const unsigned maskHi = (p == 0) ? 0u : (0xFFFFFFFFu << (shift + 8));
        const unsigned prefix = st[1];
        const unsigned rem    = st[2];
        #pragma unroll
        for (int j2 = 0; j2 < 8; ++j2) hist[row * 256 + rt + 32 * j2] = 0;
        __syncthreads();
        #pragma unroll
        for (int e = 0; e < 64; ++e) {
            const unsigned u = key[e];
            if ((u & maskHi) == prefix)
                atomicAdd(&hist[row * 256 + ((u >> shift) & 255u)], 1u);
        }
        __syncthreads();
        unsigned hloc[8]; unsigned s_local = 0;
        #pragma unroll
        for (int e = 0; e < 8; ++e) { hloc[e] = hist[row * 256 + 255 - 8 * rt - e]; s_local += hloc[e]; }
        unsigned inc = s_local;
        #pragma unroll
        for (int d = 1; d < 32; d <<= 1) {
            const unsigned o = (unsigned)__shfl_up((int)inc, (unsigned)d, 32);
            if (rt >= d) inc += o;
        }
        const unsigned s_above = inc - s_local;
        if (s_above < rem && s_above + s_local >= rem) {
            unsigned cum = s_above;
            #pragma unroll
            for (int e = 0; e < 8; ++e) {
                const unsigned c2 = hloc[e];
                if (cum + c2 >= rem) {
                    st[1] = prefix | ((unsigned)(255 - 8 * rt - e) << shift);
                    st[2] = rem - cum;
                    break;
                }
                cum += c2;
            }
        }
        __syncthreads();
    }
    const unsigned t      = st[1];
    const unsigned rem_eq = st[2];

    {   // tie handling (lowest-index-first); rare
        unsigned cE = 0;
        #pragma unroll
        for (int e = 0; e < 64; ++e) cE += (key[e] == t) ? 1u : 0u;
        #pragma unroll
        for (int d = 16; d >= 1; d >>= 1) cE += (unsigned)__shfl_xor((int)cE, d, 32);
        if (rt == 0 && cE > rem_eq) {
            unsigned c2 = 0;
            for (int k = 0; k < SEQ; ++k)
                if (fkey(scores[SIDX(row, k)]) == t) { if (++c2 == rem_eq) { st[4] = (unsigned)k; break; } }
        }
    }
    __syncthreads();           // all tie-scans done; scores may now be overlaid
    const int icut = (int)st[4];

    // ---- P = exp(s - m) on selected, 0 elsewhere; bf16 hi/lo overlay + denom
    unsigned short* PH = (unsigned short*)smem;
    unsigned short* PL = PH + QB * SEQ;
    {
        float psum = 0.f;
        #pragma unroll
        for (int j = 0; j < 16; ++j) {
            const int G = rt + 32 * j;
            const int gx = G ^ cx;
            unsigned short ph[4], pl[4];
            #pragma unroll
            for (int e = 0; e < 4; ++e) {
                const unsigned u = key[4*j+e];
                const int k = 4 * gx + e;
                float pv = 0.f;
                if (u > t || (u == t && k <= icut)) { pv = __expf(fival(u) - mrow); psum += pv; }
                const unsigned short hh = bf16h(pv);
                ph[e] = hh;
                pl[e] = bf16h(pv - bf16f(hh));
            }
            const int g16 = (gx >> 1) ^ cx;
            const int off = (row << 11) + (g16 << 3) + ((gx & 1) << 2);
            uint2 wph; wph.x = (unsigned)ph[0] | ((unsigned)ph[1] << 16);
            wph.y = (unsigned)ph[2] | ((unsigned)ph[3] << 16);
            *(uint2*)&PH[off] = wph;
            uint2 wpl; wpl.x = (unsigned)pl[0] | ((unsigned)pl[1] << 16);
            wpl.y = (unsigned)pl[2] | ((unsigned)pl[3] << 16);
            *(uint2*)&PL[off] = wpl;
        }
        #pragma unroll
        for (int d = 16; d >= 1; d >>= 1) psum += __shfl_xor(psum, d, 32);
        if (rt == 0) st[5] = __float_as_uint(1.0f / psum);
    }
    __syncthreads();

    // ---- PV via MFMA: wave = (dh-tile, kv-half); split P x single-bf16 V
    {
        const int dt = wv & 3, hf = wv >> 2;
        const int coll = lane & 15, kg = lane >> 4;
        const int c8 = coll & 7;
        f32x4 acc = {};
        for (int kc = 0; kc < 32; ++kc) {
            const int kv0 = hf * 1024 + kc * 32 + kg * 8;
            const int aoff = (coll << 11) + (((kv0 >> 3) ^ c8) << 3);
            const short8 pa = *(const short8*)&PH[aoff];
            const short8 pb = *(const short8*)&PL[aoff];
            const short8 bv = *(const short8*)&Vf[(((size_t)bh * 4 + dt) * 64 + hf * 32 + kc) * 512 + lane * 8];
            acc = __builtin_amdgcn_mfma_f32_16x16x32_bf16(pa, bv, acc, 0, 0, 0);
            acc = __builtin_amdgcn_mfma_f32_16x16x32_bf16(pb, bv, acc, 0, 0, 0);
        }
        float* red = (float*)hist;
        if (hf == 1) *(f32x4*)&red[(dt * 64 + lane) << 2] = acc;
        __syncthreads();
        if (hf == 0) {
            const f32x4 o = *(const f32x4*)&red[(dt * 64 + lane) << 2];
            #pragma unroll
            for (int r = 0; r < 4; ++r) {
                const int rw = (lane >> 4) * 4 + r;
                const float inv = __uint_as_float(state[rw * 8 + 5]);
                const float v = (acc[r] + o[r]) * inv;
                const int n = h * 64 + dt * 16 + coll;
                const int m = b * SEQ + q0 + rw;
                const int mblk = m >> 4, mrow = m & 15;
                const int ks = n >> 5, kg2 = (n >> 3) & 3, j2 = n & 7;
                const size_t a2 = (((size_t)mblk * 24 + ks) * 64 + kg2 * 16 + mrow) * 8 + j2;
                const unsigned short vh = bf16h(v);
                AOh[a2] = vh;
                AOl[a2] = bf16h(v - bf16f(vh));
            }
        }
    }
}

// ---------------------------------------------------------------------------
extern "C" void kernel_launch(void* const* d_in, const int* in_sizes, int n_in,
                              void* d_out, int out_size, void* d_ws, size_t ws_size,
                              hipStream_t stream)
{
    const float* x  = (const float*)d_in[0];
    const float* Wq = (const float*)d_in[1];
    const float* bq = (const float*)d_in[2];
    const float* Wk = (const float*)d_in[3];
    const float* bk = (const float*)d_in[4];
    const float* Wv = (const float*)d_in[5];
    const float* bv = (const float*)d_in[6];
    const float* Wo = (const float*)d_in[7];
    const float* bo = (const float*)d_in[8];

    unsigned short* U = (unsigned short*)d_ws;
    const size_t SZ = (size_t)BATCH * SEQ * HIDDEN;   // 3,145,728
    const size_t WSZ = (size_t)HIDDEN * HIDDEN;       //   589,824
    unsigned short* xh  = U;                // later reused as AOh
    unsigned short* xl  = U + SZ;           // later reused as AOl
    unsigned short* Qh  = U + 2 * SZ;
    unsigned short* Ql  = U + 3 * SZ;
    unsigned short* Kh  = U + 4 * SZ;
    unsigned short* Kl  = U + 5 * SZ;
    unsigned short* Vt  = U + 6 * SZ;
    unsigned short* wth = U + 7 * SZ;
    unsigned short* wtl = wth + WSZ;
    unsigned short* woh = wtl + WSZ;
    unsigned short* wol = woh + WSZ;

    const dim3 gg(HIDDEN / 64, (BATCH * SEQ) / 64);

    cvt_frag<<<1536, 256, 0, stream>>>(x, xh, xl, BATCH * SEQ);
    cvt_frag<<<288, 256, 0, stream>>>(Wo, woh, wol, HIDDEN);

    cvt_frag<<<288, 256, 0, stream>>>(Wq, wth, wtl, HIDDEN);
    proj_mfma<0><<<gg, 256, 0, stream>>>(xh, xl, wth, wtl, bq, Qh, Ql);
    cvt_frag<<<288, 256, 0, stream>>>(Wk, wth, wtl, HIDDEN);
    proj_mfma<0><<<gg, 256, 0, stream>>>(xh, xl, wth, wtl, bk, Kh, Kl);
    cvt_frag<<<288, 256, 0, stream>>>(Wv, wth, wtl, HIDDEN);
    proj_mfma<1><<<gg, 256, 0, stream>>>(xh, xl, wth, wtl, bv, Vt, (unsigned short*)nullptr);

    const int shbytes = (QB * SEQ + QB * 256 + QB * 8) * 4;   // 147,968 B
    hipFuncSetAttribute((const void*)sparse_attn,
                        hipFuncAttributeMaxDynamicSharedMemorySize, shbytes);
    sparse_attn<<<dim3(SEQ / QB, HEADS, BATCH), NTH, shbytes, stream>>>(
        Qh, Ql, Kh, Kl, Vt, xh, xl);

    gemm_out<<<gg, 256, 0, stream>>>(xh, xl, woh, wol, bo, (float*)d_out);
}

// Round 5
// 564.946 us; speedup vs baseline: 5.0806x; 1.1066x over previous
//
#include <hip/hip_runtime.h>
#include <math.h>

#define HIDDEN 768
#define HEADS 12
#define HD 64
#define SEQ 2048
#define BATCH 2
#define KK 204
#define QB 16
#define NTH 1024

typedef __attribute__((ext_vector_type(8))) short short8;
typedef __attribute__((ext_vector_type(4))) float f32x4;

// monotonic float->uint key (larger float => larger key)
__device__ __forceinline__ unsigned fkey(float f) {
    unsigned u = __float_as_uint(f);
    return u ^ ((unsigned)((int)u >> 31) | 0x80000000u);
}
__device__ __forceinline__ float fival(unsigned k) {
    unsigned u = k ^ ((k & 0x80000000u) ? 0x80000000u : 0xFFFFFFFFu);
    return __uint_as_float(u);
}
__device__ __forceinline__ unsigned short bf16h(float f) {
    unsigned u = __float_as_uint(f);
    return (unsigned short)((u + 0x7FFFu + ((u >> 16) & 1u)) >> 16);
}
__device__ __forceinline__ float bf16f(unsigned short h) {
    return __uint_as_float(((unsigned)h) << 16);
}

// swizzled fp32 score LDS index (float4-group XOR row&7) — row stride 2048
#define SIDX(r,k) (((r)<<11) + (((((k)>>2) ^ ((r)&7))) << 2) + ((k)&3))

// ---------------------------------------------------------------------------
// Convert fp32 row-major [rows x 768] into MFMA fragment layout bf16 hi/lo:
// out[(rblk*24 + kc)*64 + lane][j] with lane = kg*16 + (r&15), j = k&7.
// ---------------------------------------------------------------------------
__global__ __launch_bounds__(256)
void cvt_frag(const float* __restrict__ in, unsigned short* __restrict__ oh,
              unsigned short* __restrict__ ol, int rows)
{
    const int t = blockIdx.x * 256 + threadIdx.x;
    if (t >= rows * 96) return;
    const int lane = t & 63;
    const int kc   = (t >> 6) % 24;
    const int rblk = t / (24 * 64);
    const int r = rblk * 16 + (lane & 15);
    const int k = kc * 32 + (lane >> 4) * 8;
    const float4 a = *(const float4*)&in[(size_t)r * 768 + k];
    const float4 b = *(const float4*)&in[(size_t)r * 768 + k + 4];
    const float v[8] = {a.x, a.y, a.z, a.w, b.x, b.y, b.z, b.w};
    short8 sh, sl;
    #pragma unroll
    for (int j = 0; j < 8; ++j) {
        const unsigned short hh = bf16h(v[j]);
        sh[j] = (short)hh;
        sl[j] = (short)bf16h(v[j] - bf16f(hh));
    }
    *(short8*)&oh[(size_t)t * 8] = sh;
    *(short8*)&ol[(size_t)t * 8] = sl;
}

// ---------------------------------------------------------------------------
// Projection GEMM via split-bf16 MFMA: y = x @ W^T + b, M=4096, N=K=768.
// MODE 0: output bf16 hi/lo in attn Q/K fragment layout
// MODE 1: output bf16 hi in attn V fragment layout
// ---------------------------------------------------------------------------
template<int MODE>
__global__ __launch_bounds__(256)
void proj_mfma(const unsigned short* __restrict__ Ah, const unsigned short* __restrict__ Al,
               const unsigned short* __restrict__ Bh, const unsigned short* __restrict__ Bl,
               const float* __restrict__ bias,
               unsigned short* __restrict__ Oh, unsigned short* __restrict__ Ol)
{
    const int w = threadIdx.x >> 6, lane = threadIdx.x & 63;
    const int n0 = blockIdx.x * 64;
    const int m0 = blockIdx.y * 64 + w * 16;
    const int mblk = m0 >> 4;
    f32x4 acc[4] = {};
    for (int kc = 0; kc < 24; ++kc) {
        const short8 ah = *(const short8*)&Ah[((size_t)(mblk * 24 + kc) * 64 + lane) * 8];
        const short8 al = *(const short8*)&Al[((size_t)(mblk * 24 + kc) * 64 + lane) * 8];
        #pragma unroll
        for (int nt = 0; nt < 4; ++nt) {
            const int nblk = (n0 >> 4) + nt;
            const short8 bh8 = *(const short8*)&Bh[((size_t)(nblk * 24 + kc) * 64 + lane) * 8];
            const short8 bl8 = *(const short8*)&Bl[((size_t)(nblk * 24 + kc) * 64 + lane) * 8];
            acc[nt] = __builtin_amdgcn_mfma_f32_16x16x32_bf16(ah, bh8, acc[nt], 0, 0, 0);
            acc[nt] = __builtin_amdgcn_mfma_f32_16x16x32_bf16(ah, bl8, acc[nt], 0, 0, 0);
            acc[nt] = __builtin_amdgcn_mfma_f32_16x16x32_bf16(al, bh8, acc[nt], 0, 0, 0);
        }
    }
    const int col = lane & 15, rg = lane >> 4;
    #pragma unroll
    for (int nt = 0; nt < 4; ++nt) {
        const int n = n0 + nt * 16 + col;
        const int h = n >> 6, dh = n & 63;
        const float bb = bias[n];
        #pragma unroll
        for (int r = 0; r < 4; ++r) {
            const int m = m0 + rg * 4 + r;
            const int b = m >> 11, s = m & (SEQ - 1);
            const float v = acc[nt][r] + bb;
            const unsigned short vh = bf16h(v);
            if (MODE == 0) {
                const int t = s >> 4, colq = s & 15;
                const int ks = dh >> 5, kg = (dh >> 3) & 3, j = dh & 7;
                const size_t addr = ((((size_t)(b * HEADS + h) * 128 + t) * 2 + ks) * 64 + kg * 16 + colq) * 8 + j;
                Oh[addr] = vh;
                Ol[addr] = bf16h(v - bf16f(vh));
            } else {
                const int dt = dh >> 4, colv = dh & 15;
                const int kc2 = s >> 5, kg = (s >> 3) & 3, j = s & 7;
                const size_t addr = ((((size_t)(b * HEADS + h) * 4 + dt) * 64 + kc2) * 64 + kg * 16 + colv) * 8 + j;
                Oh[addr] = vh;
            }
        }
    }
}

// ---------------------------------------------------------------------------
// Output GEMM: out = AO @ Wo^T + bo (fp32 out), AO/Wo in fragment layout.
// ---------------------------------------------------------------------------
__global__ __launch_bounds__(256)
void gemm_out(const unsigned short* __restrict__ Ah, const unsigned short* __restrict__ Al,
              const unsigned short* __restrict__ Bh, const unsigned short* __restrict__ Bl,
              const float* __restrict__ bias, float* __restrict__ out)
{
    const int w = threadIdx.x >> 6, lane = threadIdx.x & 63;
    const int n0 = blockIdx.x * 64;
    const int m0 = blockIdx.y * 64 + w * 16;
    const int mblk = m0 >> 4;
    f32x4 acc[4] = {};
    for (int kc = 0; kc < 24; ++kc) {
        const short8 ah = *(const short8*)&Ah[((size_t)(mblk * 24 + kc) * 64 + lane) * 8];
        const short8 al = *(const short8*)&Al[((size_t)(mblk * 24 + kc) * 64 + lane) * 8];
        #pragma unroll
        for (int nt = 0; nt < 4; ++nt) {
            const int nblk = (n0 >> 4) + nt;
            const short8 bh8 = *(const short8*)&Bh[((size_t)(nblk * 24 + kc) * 64 + lane) * 8];
            const short8 bl8 = *(const short8*)&Bl[((size_t)(nblk * 24 + kc) * 64 + lane) * 8];
            acc[nt] = __builtin_amdgcn_mfma_f32_16x16x32_bf16(ah, bh8, acc[nt], 0, 0, 0);
            acc[nt] = __builtin_amdgcn_mfma_f32_16x16x32_bf16(ah, bl8, acc[nt], 0, 0, 0);
            acc[nt] = __builtin_amdgcn_mfma_f32_16x16x32_bf16(al, bh8, acc[nt], 0, 0, 0);
        }
    }
    const int col = lane & 15, rg = lane >> 4;
    #pragma unroll
    for (int nt = 0; nt < 4; ++nt) {
        const int n = n0 + nt * 16 + col;
        const float bb = bias[n];
        #pragma unroll
        for (int r = 0; r < 4; ++r) {
            const int m = m0 + rg * 4 + r;
            out[(size_t)m * HIDDEN + n] = acc[nt][r] + bb;
        }
    }
}

// ---------------------------------------------------------------------------
// Fused sparse attention, 16-wave edition. 1024 thr / (16 q-rows, h, b).
// Wave wv: phase A computes 8 k-tiles; phase B/P: row wv (one wave = one
// row team, width-64 shuffles); PV: wave = (kv-slice, dh-tile) + reduction.
// ---------------------------------------------------------------------------
__global__ __launch_bounds__(NTH, 4)
void sparse_attn(const unsigned short* __restrict__ Qfh, const unsigned short* __restrict__ Qfl,
                 const unsigned short* __restrict__ Kfh, const unsigned short* __restrict__ Kfl,
                 const unsigned short* __restrict__ Vf,
                 unsigned short* __restrict__ AOh, unsigned short* __restrict__ AOl)
{
    extern __shared__ float smem[];
    float*    scores = smem;                           // 16*2048 f32 swizzled; later Ph/Pl overlay
    unsigned* hist   = (unsigned*)(smem + QB * SEQ);   // 16*256 (radix) / PV partial-C (16KB)
    unsigned* state  = hist + QB * 256;                // 16*8

    const int tid = threadIdx.x;
    const int wv = tid >> 6, lane = tid & 63;
    const int qb = blockIdx.x;
    const int q0 = qb * QB;
    const int h = blockIdx.y, b = blockIdx.z;
    const int bh = b * HEADS + h;

    if (lane == 0) {                 // one wave per row: init own row state
        unsigned* s0 = state + wv * 8;
        s0[1] = 0; s0[2] = KK; s0[4] = SEQ;
    }

    // ---- Phase A: scores = Q K^T / 8 (6 MFMA per 16x16 tile), 8 tiles/wave
    {
        const size_t qbase = ((size_t)bh * 128 + qb) * 1024;
        const short8 qh0 = *(const short8*)&Qfh[qbase + lane * 8];
        const short8 qh1 = *(const short8*)&Qfh[qbase + 512 + lane * 8];
        const short8 ql0 = *(const short8*)&Qfl[qbase + lane * 8];
        const short8 ql1 = *(const short8*)&Qfl[qbase + 512 + lane * 8];
        const int col = lane & 15, rg = lane >> 4;
        for (int i = 0; i < 8; ++i) {
            const int t = wv * 8 + i;
            const size_t kb = ((size_t)bh * 128 + t) * 1024 + lane * 8;
            const short8 kh0 = *(const short8*)&Kfh[kb];
            const short8 kh1 = *(const short8*)&Kfh[kb + 512];
            const short8 kl0 = *(const short8*)&Kfl[kb];
            const short8 kl1 = *(const short8*)&Kfl[kb + 512];
            f32x4 c = {};
            c = __builtin_amdgcn_mfma_f32_16x16x32_bf16(qh0, kh0, c, 0, 0, 0);
            c = __builtin_amdgcn_mfma_f32_16x16x32_bf16(qh1, kh1, c, 0, 0, 0);
            c = __builtin_amdgcn_mfma_f32_16x16x32_bf16(qh0, kl0, c, 0, 0, 0);
            c = __builtin_amdgcn_mfma_f32_16x16x32_bf16(qh1, kl1, c, 0, 0, 0);
            c = __builtin_amdgcn_mfma_f32_16x16x32_bf16(ql0, kh0, c, 0, 0, 0);
            c = __builtin_amdgcn_mfma_f32_16x16x32_bf16(ql1, kh1, c, 0, 0, 0);
            const int k = t * 16 + col;
            #pragma unroll
            for (int r = 0; r < 4; ++r) {
                const int row = rg * 4 + r;
                scores[SIDX(row, k)] = c[r] * 0.125f;
            }
        }
    }
    __syncthreads();

    // ---- Phase B: exact top-KK per row; row = wave, 32 keys/lane in VGPRs
    const int row = wv, rt = lane;
    unsigned* st = state + row * 8;
    const int cx = row & 7;
    unsigned key[32];
    {
        const float4* srow4 = (const float4*)(scores + (row << 11));
        #pragma unroll
        for (int j = 0; j < 8; ++j) {
            const float4 v = srow4[rt + 64 * j];
            key[4*j+0] = fkey(v.x); key[4*j+1] = fkey(v.y);
            key[4*j+2] = fkey(v.z); key[4*j+3] = fkey(v.w);
        }
    }
    unsigned mk = 0;
    #pragma unroll
    for (int e = 0; e < 32; ++e) mk = max(mk, key[e]);
    #pragma unroll
    for (int d = 32; d >= 1; d >>= 1)
        mk = max(mk, (unsigned)__shfl_xor((int)mk, d, 64));
    const float mrow = fival(mk);

    for (int p = 0; p < 4; ++p) {
        const int shift = 24 - (p << 3);
        const unsigned maskHi = (p == 0) ? 0u : (0xFFFFFFFFu << (shift + 8));
        const unsigned prefix = st[1];
        const unsigned rem    = st[2];
        #pragma unroll
        for (int j2 = 0; j2 < 4; ++j2) hist[row * 256 + rt + 64 * j2] = 0;
        __syncthreads();
        #pragma unroll
        for (int e = 0; e < 32; ++e) {
            const unsigned u = key[e];
            if ((u & maskHi) == prefix)
                atomicAdd(&hist[row * 256 + ((u >> shift) & 255u)], 1u);
        }
        __syncthreads();
        // descending scan: lane rt owns bins [255-4rt .. 252-4rt]
        unsigned hloc[4]; unsigned s_local = 0;
        #pragma unroll
        for (int e = 0; e < 4; ++e) { hloc[e] = hist[row * 256 + 255 - 4 * rt - e]; s_local += hloc[e]; }
        unsigned inc = s_local;
        #pragma unroll
        for (int d = 1; d < 64; d <<= 1) {
            const unsigned o = (unsigned)__shfl_up((int)inc, (unsigned)d, 64);
            if (rt >= d) inc += o;
        }
        const unsigned s_above = inc - s_local;
        if (s_above < rem && s_above + s_local >= rem) {
            unsigned cum = s_above;
            #pragma unroll
            for (int e = 0; e < 4; ++e) {
                const unsigned c2 = hloc[e];
                if (cum + c2 >= rem) {
                    st[1] = prefix | ((unsigned)(255 - 4 * rt - e) << shift);
                    st[2] = rem - cum;
                    break;
                }
                cum += c2;
            }
        }
        __syncthreads();
    }
    const unsigned t      = st[1];
    const unsigned rem_eq = st[2];

    {   // tie handling (lowest-index-first); rare
        unsigned cE = 0;
        #pragma unroll
        for (int e = 0; e < 32; ++e) cE += (key[e] == t) ? 1u : 0u;
        #pragma unroll
        for (int d = 32; d >= 1; d >>= 1) cE += (unsigned)__shfl_xor((int)cE, d, 64);
        if (rt == 0 && cE > rem_eq) {
            unsigned c2 = 0;
            for (int k = 0; k < SEQ; ++k)
                if (fkey(scores[SIDX(row, k)]) == t) { if (++c2 == rem_eq) { st[4] = (unsigned)k; break; } }
        }
    }
    __syncthreads();           // all tie-scans done; scores may now be overlaid
    const int icut = (int)st[4];

    // ---- P = exp(s - m) on selected, 0 elsewhere; bf16 hi/lo overlay + denom
    unsigned short* PH = (unsigned short*)smem;
    unsigned short* PL = PH + QB * SEQ;
    {
        float psum = 0.f;
        #pragma unroll
        for (int j = 0; j < 8; ++j) {
            const int G = rt + 64 * j;
            const int gx = G ^ cx;
            unsigned short ph[4], pl[4];
            #pragma unroll
            for (int e = 0; e < 4; ++e) {
                const unsigned u = key[4*j+e];
                const int k = 4 * gx + e;
                float pv = 0.f;
                if (u > t || (u == t && k <= icut)) { pv = __expf(fival(u) - mrow); psum += pv; }
                const unsigned short hh = bf16h(pv);
                ph[e] = hh;
                pl[e] = bf16h(pv - bf16f(hh));
            }
            const int g16 = (gx >> 1) ^ cx;
            const int off = (row << 11) + (g16 << 3) + ((gx & 1) << 2);
            uint2 wph; wph.x = (unsigned)ph[0] | ((unsigned)ph[1] << 16);
            wph.y = (unsigned)ph[2] | ((unsigned)ph[3] << 16);
            *(uint2*)&PH[off] = wph;
            uint2 wpl; wpl.x = (unsigned)pl[0] | ((unsigned)pl[1] << 16);
            wpl.y = (unsigned)pl[2] | ((unsigned)pl[3] << 16);
            *(uint2*)&PL[off] = wpl;
        }
        #pragma unroll
        for (int d = 32; d >= 1; d >>= 1) psum += __shfl_xor(psum, d, 64);
        if (rt == 0) st[5] = __float_as_uint(1.0f / psum);
    }
    __syncthreads();

    // ---- PV via MFMA: wave = (kv-slice kq, dh-tile dt); split P x bf16 V
    {
        const int dt = wv & 3, kq = wv >> 2;
        const int coll = lane & 15, kg = lane >> 4;
        const int c8 = coll & 7;
        f32x4 acc = {};
        for (int kc = 0; kc < 16; ++kc) {
            const int kv0 = kq * 512 + kc * 32 + kg * 8;
            const int aoff = (coll << 11) + (((kv0 >> 3) ^ c8) << 3);
            const short8 pa = *(const short8*)&PH[aoff];
            const short8 pb = *(const short8*)&PL[aoff];
            const int kc2 = kq * 16 + kc;
            const short8 bv = *(const short8*)&Vf[(((size_t)bh * 4 + dt) * 64 + kc2) * 512 + lane * 8];
            acc = __builtin_amdgcn_mfma_f32_16x16x32_bf16(pa, bv, acc, 0, 0, 0);
            acc = __builtin_amdgcn_mfma_f32_16x16x32_bf16(pb, bv, acc, 0, 0, 0);
        }
        float* red = (float*)hist;
        if (kq > 0) *(f32x4*)&red[(((kq - 1) * 4 + dt) * 64 + lane) << 2] = acc;
        __syncthreads();
        if (kq == 0) {
            #pragma unroll
            for (int q2 = 0; q2 < 3; ++q2) {
                const f32x4 o = *(const f32x4*)&red[((q2 * 4 + dt) * 64 + lane) << 2];
                acc[0] += o[0]; acc[1] += o[1]; acc[2] += o[2]; acc[3] += o[3];
            }
            #pragma unroll
            for (int r = 0; r < 4; ++r) {
                const int rw = (lane >> 4) * 4 + r;
                const float inv = __uint_as_float(state[rw * 8 + 5]);
                const float v = acc[r] * inv;
                const int n = h * 64 + dt * 16 + coll;
                const int m = b * SEQ + q0 + rw;
                const int mblk = m >> 4, mrow2 = m & 15;
                const int ks = n >> 5, kg2 = (n >> 3) & 3, j2 = n & 7;
                const size_t a2 = (((size_t)mblk * 24 + ks) * 64 + kg2 * 16 + mrow2) * 8 + j2;
                const unsigned short vh = bf16h(v);
                AOh[a2] = vh;
                AOl[a2] = bf16h(v - bf16f(vh));
            }
        }
    }
}

// ---------------------------------------------------------------------------
extern "C" void kernel_launch(void* const* d_in, const int* in_sizes, int n_in,
                              void* d_out, int out_size, void* d_ws, size_t ws_size,
                              hipStream_t stream)
{
    const float* x  = (const float*)d_in[0];
    const float* Wq = (const float*)d_in[1];
    const float* bq = (const float*)d_in[2];
    const float* Wk = (const float*)d_in[3];
    const float* bk = (const float*)d_in[4];
    const float* Wv = (const float*)d_in[5];
    const float* bv = (const float*)d_in[6];
    const float* Wo = (const float*)d_in[7];
    const float* bo = (const float*)d_in[8];

    unsigned short* U = (unsigned short*)d_ws;
    const size_t SZ = (size_t)BATCH * SEQ * HIDDEN;   // 3,145,728
    const size_t WSZ = (size_t)HIDDEN * HIDDEN;       //   589,824
    unsigned short* xh  = U;                // later reused as AOh
    unsigned short* xl  = U + SZ;           // later reused as AOl
    unsigned short* Qh  = U + 2 * SZ;
    unsigned short* Ql  = U + 3 * SZ;
    unsigned short* Kh  = U + 4 * SZ;
    unsigned short* Kl  = U + 5 * SZ;
    unsigned short* Vt  = U + 6 * SZ;
    unsigned short* wth = U + 7 * SZ;
    unsigned short* wtl = wth + WSZ;
    unsigned short* woh = wtl + WSZ;
    unsigned short* wol = woh + WSZ;

    const dim3 gg(HIDDEN / 64, (BATCH * SEQ) / 64);

    cvt_frag<<<1536, 256, 0, stream>>>(x, xh, xl, BATCH * SEQ);
    cvt_frag<<<288, 256, 0, stream>>>(Wo, woh, wol, HIDDEN);

    cvt_frag<<<288, 256, 0, stream>>>(Wq, wth, wtl, HIDDEN);
    proj_mfma<0><<<gg, 256, 0, stream>>>(xh, xl, wth, wtl, bq, Qh, Ql);
    cvt_frag<<<288, 256, 0, stream>>>(Wk, wth, wtl, HIDDEN);
    proj_mfma<0><<<gg, 256, 0, stream>>>(xh, xl, wth, wtl, bk, Kh, Kl);
    cvt_frag<<<288, 256, 0, stream>>>(Wv, wth, wtl, HIDDEN);
    proj_mfma<1><<<gg, 256, 0, stream>>>(xh, xl, wth, wtl, bv, Vt, (unsigned short*)nullptr);

    const int shbytes = (QB * SEQ + QB * 256 + QB * 8) * 4;   // 147,968 B
    hipFuncSetAttribute((const void*)sparse_attn,
                        hipFuncAttributeMaxDynamicSharedMemorySize, shbytes);
    sparse_attn<<<dim3(SEQ / QB, HEADS, BATCH), NTH, shbytes, stream>>>(
        Qh, Ql, Kh, Kl, Vt, xh, xl);

    gemm_out<<<gg, 256, 0, stream>>>(xh, xl, woh, wol, bo, (float*)d_out);
}